// Round 6
// baseline (321.310 us; speedup 1.0000x reference)
//
#include <hip/hip_runtime.h>

// ============================================================================
// ETC layer: windowed rel-pos attention + FFN, bf16 MFMA GEMMs on gfx950
//   B=2 S=2048 D_MODEL=1024 NHEAD=16 DHEAD=64 DFF=4096 R=25 W=51 K=5
// R14: revert GEMMs to R12's gemm_dp (best verified: 307.46us). R13's
//   8-phase port regressed (QKV 59us, MfmaUtil 16%): at K=1024/NITER=8,
//   added barriers+lgkm drains only subtract; all schedule variants
//   (R9/R10/R12/R13) plateau at ~740 TF -> structural at these shapes.
//   This round cuts certain HBM traffic instead:
//   - WO  split-K 4 -> 2 (grid 256, K=512/slice):  -32 MB partial traffic
//   - FF2 split-K 4 -> 2 (grid 256, K=2048/slice): -32 MB partial traffic
//   ln1/ln2 read 2 partials. Everything else identical to R12.
// ============================================================================

#define D_MODEL 1024
#define SEQ     2048
#define NROWS   4096      // B*S
#define WIN     51
#define RAD     25

typedef __attribute__((ext_vector_type(8))) __bf16 bf16x8;
typedef __attribute__((ext_vector_type(4))) float  floatx4;

__device__ __forceinline__ unsigned short f2bf(float x) {
    unsigned u = __float_as_uint(x);
    unsigned r = u + 0x7fffu + ((u >> 16) & 1u);
    return (unsigned short)(r >> 16);
}
__device__ __forceinline__ float bf2f(unsigned short h) {
    return __uint_as_float(((unsigned)h) << 16);
}

// async global->LDS 16B per lane; LDS dest = wave-uniform base + lane*16
__device__ __forceinline__ void gld16(const unsigned short* g, unsigned short* l) {
    __builtin_amdgcn_global_load_lds(
        (const __attribute__((address_space(1))) unsigned int*)g,
        (__attribute__((address_space(3))) unsigned int*)l,
        16, 0, 0);
}

// ---------------------------------------------------------------------------
// One-shot conversion kernel (unchanged).
// ---------------------------------------------------------------------------
__device__ __forceinline__ void cvtgrp(const float* __restrict__ in,
                                       unsigned short* __restrict__ out, int g) {
    float4 f = ((const float4*)in)[g];
    ushort4 u;
    u.x = f2bf(f.x); u.y = f2bf(f.y); u.z = f2bf(f.z); u.w = f2bf(f.w);
    ((ushort4*)out)[g] = u;
}

__global__ __launch_bounds__(256)
void cvt_all(const float* __restrict__ src,
             const float* __restrict__ wq, const float* __restrict__ wk,
             const float* __restrict__ wv, const float* __restrict__ wo,
             const float* __restrict__ w1, const float* __restrict__ w2,
             const float* __restrict__ bq, const float* __restrict__ bk,
             const float* __restrict__ bv,
             unsigned short* __restrict__ xb,
             unsigned short* __restrict__ wqkvb,
             unsigned short* __restrict__ wob,
             unsigned short* __restrict__ w1b,
             unsigned short* __restrict__ w2b,
             float* __restrict__ bqkv)
{
    int g = blockIdx.x * 256 + threadIdx.x;
    if (g >= 4194496) return;
    if (g < 1048576) { cvtgrp(src, xb, g); return; }
    g -= 1048576;
    if (g < 262144) { cvtgrp(wq, wqkvb, g); return; }
    g -= 262144;
    if (g < 262144) { cvtgrp(wk, wqkvb + 1048576, g); return; }
    g -= 262144;
    if (g < 262144) { cvtgrp(wv, wqkvb + 2097152, g); return; }
    g -= 262144;
    if (g < 262144) { cvtgrp(wo, wob, g); return; }
    g -= 262144;
    if (g < 1048576) { cvtgrp(w1, w1b, g); return; }
    g -= 1048576;
    if (g < 1048576) { cvtgrp(w2, w2b, g); return; }
    g -= 1048576;
    float4 f = (g < 64) ? ((const float4*)bq)[g]
             : (g < 128) ? ((const float4*)bk)[g - 64]
                         : ((const float4*)bv)[g - 128];
    ((float4*)bqkv)[g] = f;
}

// ---------------------------------------------------------------------------
// GEMM: 256x128 tile, BK=32, 256 threads (4 waves 2Mx2N; 128x64 out/wave).
// LDS: A triple-buffered 3x[256x32] (48KB) + B 3x[128x32] (24KB) = 72KB
//   -> 2 blocks/CU. Depth-2 global_load_lds prefetch (6 loads/thread/tile:
//   A x4 + B x2), certify tile t+1 at end of tile t with counted vmcnt(6)
//   + s_barrier (never drains to 0 mid-loop).
// Swizzle: 16B-chunk involution f(ci)=ci^((ci>>3)&7) per buffer; applied to
//   the global SOURCE of global_load_lds (LDS dest linear) and to ds_read
//   chunk addresses.
// Correctness: identical structure to R12 (passed).
// ---------------------------------------------------------------------------
__global__ __launch_bounds__(256, 2)
void gemm_dp(const unsigned short* __restrict__ A,
             const unsigned short* __restrict__ Wt,
             const float* __restrict__ bias,
             unsigned short* __restrict__ Cb,
             int kstride, int kloop, int T, int tncnt,
             int ldc, int relu, size_t sstep1, size_t sstep2)
{
    __shared__ __attribute__((aligned(16))) unsigned short AS[3 * 8192];
    __shared__ __attribute__((aligned(16))) unsigned short BS[3 * 4096];

    const int id = blockIdx.x;
    const int s  = id / T;
    const int t0 = id - s * T;
    const int sid = (t0 & 7) * (T >> 3) + (t0 >> 3);   // XCD-contiguous
    const int bm = (sid / tncnt) * 256;
    const int bn = (sid % tncnt) * 128;

    const int tid  = threadIdx.x;
    const int lane = tid & 63;
    const int wave = tid >> 6;
    const int wr   = wave >> 1;          // 0..1
    const int wc   = wave & 1;           // 0..1
    const int fm   = lane & 15;
    const int fq   = lane >> 4;

    const int kofs = s * kloop;
    const int NT   = kloop >> 5;         // BK=32 tiles

    // staging: thread's LDS dest chunk ci = i*256+tid (linear); source is the
    // inverse-swizzled global chunk gi = ci ^ ((ci>>3)&7).
    const int ks  = (tid >> 3) & 7;
    const int gi  = tid ^ ks;            // 0..255
    const int r0s = gi >> 2;             // global row 0..63 (issue 0)
    const int c2s = gi & 3;              // global 16B chunk in row
    const unsigned short* Agp = A  + (size_t)(bm + r0s) * kstride + kofs + c2s * 8;
    const unsigned short* Wgp = Wt + (size_t)(bn + r0s) * kstride + kofs + c2s * 8;
    const size_t istep = (size_t)64 * kstride;   // +64 rows per issue

    // swizzled ds_read chunk offsets (ushort units)
    const int rA  = wr * 128 + fm;
    const int rB  = wc * 64  + fm;
    const int c0A = ((((rA << 2) | fq) ^ (fm >> 1)) << 3);
    const int c0B = ((((rB << 2) | fq) ^ (fm >> 1)) << 3);

    // ---- prologue: stage tiles 0 (buf0) and 1 (buf1) ----
    {
        const unsigned short* Ap = Agp;
        const unsigned short* Wp = Wgp;
        gld16(Ap,             AS + tid * 8);
        gld16(Ap + istep,     AS + tid * 8 + 2048);
        gld16(Ap + 2 * istep, AS + tid * 8 + 4096);
        gld16(Ap + 3 * istep, AS + tid * 8 + 6144);
        gld16(Wp,             BS + tid * 8);
        gld16(Wp + istep,     BS + tid * 8 + 2048);
        Ap += 32; Wp += 32;
        gld16(Ap,             AS + 8192 + tid * 8);
        gld16(Ap + istep,     AS + 8192 + tid * 8 + 2048);
        gld16(Ap + 2 * istep, AS + 8192 + tid * 8 + 4096);
        gld16(Ap + 3 * istep, AS + 8192 + tid * 8 + 6144);
        gld16(Wp,             BS + 4096 + tid * 8);
        gld16(Wp + istep,     BS + 4096 + tid * 8 + 2048);
    }
    asm volatile("s_waitcnt vmcnt(6)" ::: "memory");   // tile 0 resident
    __builtin_amdgcn_sched_barrier(0);
    __builtin_amdgcn_s_barrier();
    __builtin_amdgcn_sched_barrier(0);

    floatx4 acc[8][4] = {};
    const unsigned short* Aga = Agp + 64;   // stages tile t+2
    const unsigned short* Wga = Wgp + 64;
    int cbA = 0, cbB = 0;                   // compute buf offsets (t%3)
    int pbA = 16384, pbB = 8192;            // prefetch buf offsets ((t+2)%3)

    for (int t = 0; t < NT; t++) {
        const bool pf = (t + 2 < NT);

        bf16x8 af[8], bf[4];
        #pragma unroll
        for (int mi = 0; mi < 8; mi++)
            af[mi] = *(const bf16x8*)(AS + cbA + c0A + mi * 512);
        #pragma unroll
        for (int ni = 0; ni < 4; ni++)
            bf[ni] = *(const bf16x8*)(BS + cbB + c0B + ni * 512);

        if (pf) {   // stage tile t+2: A x4, B x2 (FIFO order matters)
            gld16(Aga,             AS + pbA + tid * 8);
            gld16(Aga + istep,     AS + pbA + tid * 8 + 2048);
            gld16(Aga + 2 * istep, AS + pbA + tid * 8 + 4096);
            gld16(Aga + 3 * istep, AS + pbA + tid * 8 + 6144);
            gld16(Wga,             BS + pbB + tid * 8);
            gld16(Wga + istep,     BS + pbB + tid * 8 + 2048);
        }

        __builtin_amdgcn_s_setprio(1);
        #pragma unroll
        for (int mi = 0; mi < 8; mi++)
            #pragma unroll
            for (int ni = 0; ni < 4; ni++)
                acc[mi][ni] = __builtin_amdgcn_mfma_f32_16x16x32_bf16(
                    af[mi], bf[ni], acc[mi][ni], 0, 0, 0);
        __builtin_amdgcn_s_setprio(0);

        // ---- certify tile t+1 resident for all waves ----
        if (t + 1 < NT) {
            if (pf) asm volatile("s_waitcnt vmcnt(6)" ::: "memory");
            else    asm volatile("s_waitcnt vmcnt(0)" ::: "memory");
            __builtin_amdgcn_sched_barrier(0);
            __builtin_amdgcn_s_barrier();
            __builtin_amdgcn_sched_barrier(0);
        }
        cbA = (cbA == 16384) ? 0 : cbA + 8192;
        cbB = (cbB == 8192)  ? 0 : cbB + 4096;
        pbA = (pbA == 16384) ? 0 : pbA + 8192;
        pbB = (pbB == 8192)  ? 0 : pbB + 4096;
        Aga += 32;
        Wga += 32;
    }

    // ---- epilogue ----
    unsigned short* Co = Cb + (size_t)(s & 1) * sstep1 + (size_t)(s >> 1) * sstep2;
    const int r0  = bm + wr * 128 + fq * 4;
    const int c0e = bn + wc * 64 + fm;
    #pragma unroll
    for (int mi = 0; mi < 8; mi++) {
        #pragma unroll
        for (int ni = 0; ni < 4; ni++) {
            const int col = c0e + ni * 16;
            const float bv = bias ? bias[col] : 0.0f;
            #pragma unroll
            for (int rr = 0; rr < 4; rr++) {
                const int row = r0 + mi * 16 + rr;
                float v = acc[mi][ni][rr] + bv;
                if (relu) v = fmaxf(v, 0.0f);
                Co[(size_t)row * ldc + col] = f2bf(v);
            }
        }
    }
}

// ---------------------------------------------------------------------------
// Banded MFMA windowed attention (unchanged).
// ---------------------------------------------------------------------------
__global__ __launch_bounds__(256, 2)
void attn_mfma(const unsigned short* __restrict__ qkv,
               const float* __restrict__ rel,
               unsigned short* __restrict__ attnb)
{
    __shared__ __attribute__((aligned(16))) unsigned short Qs[64 * 72];
    __shared__ __attribute__((aligned(16))) unsigned short Ks[128 * 72];
    __shared__ __attribute__((aligned(16))) unsigned short Vt[64 * 168];
    __shared__ __attribute__((aligned(16))) unsigned short Rs[16 * 72];
    __shared__ __attribute__((aligned(16))) unsigned short Pl[4 * 16 * 104];
    __shared__ float Qrl[4 * 16 * 12];

    const int t   = threadIdx.x;
    const int blk = blockIdx.x;
    const int st  = blk & 31;
    const int h   = (blk >> 5) & 15;
    const int b   = blk >> 9;
    const int s0  = st << 6;
    const int brow0 = b * SEQ;

    const int trow = t >> 3;
    const int tc   = (t & 7) * 8;
    const uint4 z4 = make_uint4(0, 0, 0, 0);

    #pragma unroll
    for (int p = 0; p < 2; p++) {
        int r = trow + p * 32;
        uint4 v = *(const uint4*)(qkv + (size_t)(brow0 + s0 + r) * 3072 + h * 64 + tc);
        *(uint4*)(Qs + r * 72 + tc) = v;
    }
    #pragma unroll
    for (int p = 0; p < 4; p++) {
        int kr = trow + p * 32;
        int ka = s0 - 25 + kr;
        bool in = (ka >= 0) & (ka < SEQ);
        uint4 kv = z4, vv = z4;
        if (in) {
            kv = *(const uint4*)(qkv + (size_t)(brow0 + ka) * 3072 + 1024 + h * 64 + tc);
            vv = *(const uint4*)(qkv + (size_t)(brow0 + ka) * 3072 + 2048 + h * 64 + tc);
        }
        *(uint4*)(Ks + kr * 72 + tc) = kv;
        const unsigned short* e = (const unsigned short*)&vv;
        #pragma unroll
        for (int j = 0; j < 8; j++)
            Vt[(tc + j) * 168 + kr] = e[j];
    }
    if (t < 176) {
        float4 f = ((const float4*)rel)[t];
        int fi = t * 4, rr = fi >> 6, cc = fi & 63;
        ushort4 u;
        u.x = f2bf(f.x); u.y = f2bf(f.y); u.z = f2bf(f.z); u.w = f2bf(f.w);
        *(ushort4*)(Rs + rr * 72 + cc) = u;
    } else {
        int fi = 704 + (t - 176) * 4, rr = fi >> 6, cc = fi & 63;
        *(ushort4*)(Rs + rr * 72 + cc) = make_ushort4(0, 0, 0, 0);
    }
    {
        int n = t * 4, w2 = n >> 8, rem = n & 255, rr = rem >> 4, cc = 80 + (rem & 15);
        *(ushort4*)(Pl + w2 * (16 * 104) + rr * 104 + cc) = make_ushort4(0, 0, 0, 0);
    }
    for (int idx = t; idx < 320; idx += 256) {
        int r = idx / 5, cchunk = idx % 5;
        *(uint4*)(Vt + r * 168 + 128 + cchunk * 8) = z4;
    }
    __syncthreads();

    const int wave = t >> 6;
    const int lane = t & 63;
    const int fm   = lane & 15;
    const int fk8  = (lane >> 4) * 8;
    const int S0w  = s0 + wave * 16;
    unsigned short* Plw = Pl + wave * (16 * 104);
    float* Ql = Qrl + wave * (16 * 12);

    bf16x8 qa0 = *(const bf16x8*)(Qs + (wave * 16 + fm) * 72 + fk8);
    bf16x8 qa1 = *(const bf16x8*)(Qs + (wave * 16 + fm) * 72 + fk8 + 32);

    floatx4 Sc[5];
    #pragma unroll
    for (int nt = 0; nt < 5; nt++) {
        bf16x8 kb0 = *(const bf16x8*)(Ks + (wave * 16 + nt * 16 + fm) * 72 + fk8);
        bf16x8 kb1 = *(const bf16x8*)(Ks + (wave * 16 + nt * 16 + fm) * 72 + fk8 + 32);
        floatx4 acc = {0.f, 0.f, 0.f, 0.f};
        acc = __builtin_amdgcn_mfma_f32_16x16x32_bf16(qa0, kb0, acc, 0, 0, 0);
        acc = __builtin_amdgcn_mfma_f32_16x16x32_bf16(qa1, kb1, acc, 0, 0, 0);
        Sc[nt] = acc;
    }
    {
        bf16x8 rb0 = *(const bf16x8*)(Rs + fm * 72 + fk8);
        bf16x8 rb1 = *(const bf16x8*)(Rs + fm * 72 + fk8 + 32);
        floatx4 qr = {0.f, 0.f, 0.f, 0.f};
        qr = __builtin_amdgcn_mfma_f32_16x16x32_bf16(qa0, rb0, qr, 0, 0, 0);
        qr = __builtin_amdgcn_mfma_f32_16x16x32_bf16(qa1, rb1, qr, 0, 0, 0);
        if (fm < 12) {
            #pragma unroll
            for (int reg = 0; reg < 4; reg++)
                Ql[((lane >> 4) * 4 + reg) * 12 + fm] = qr[reg];
        }
    }

    float inv[4];
    const int iq0 = (lane >> 4) * 4;
    #pragma unroll
    for (int reg = 0; reg < 4; reg++) {
        const int i = iq0 + reg;
        float sc[5];
        float mx = -1e30f;
        #pragma unroll
        for (int nt = 0; nt < 5; nt++) {
            int c   = nt * 16 + fm;
            int off = c - 25 - i;
            int ka  = S0w - 25 + c;
            bool valid = (off >= -RAD) & (off <= RAD) & (ka >= 0) & (ka < SEQ);
            int rid = min(max(off, -5), 5) + 5;
            float v = valid ? (Sc[nt][reg] + Ql[i * 12 + rid]) * 0.125f : -1e30f;
            sc[nt] = v;
            mx = fmaxf(mx, v);
        }
        #pragma unroll
        for (int o = 1; o < 16; o <<= 1) mx = fmaxf(mx, __shfl_xor(mx, o));
        float sum = 0.f;
        #pragma unroll
        for (int nt = 0; nt < 5; nt++) {
            float e = __expf(sc[nt] - mx);
            sum += e;
            Plw[i * 104 + nt * 16 + fm] = f2bf(e);
        }
        #pragma unroll
        for (int o = 1; o < 16; o <<= 1) sum += __shfl_xor(sum, o);
        inv[reg] = 1.0f / sum;
    }

    floatx4 O[4] = {};
    #pragma unroll
    for (int kc = 0; kc < 3; kc++) {
        bf16x8 pa = *(const bf16x8*)(Plw + fm * 104 + fk8 + kc * 32);
        #pragma unroll
        for (int nt = 0; nt < 4; nt++) {
            bf16x8 vb = *(const bf16x8*)(Vt + (nt * 16 + fm) * 168 + wave * 16 + fk8 + kc * 32);
            O[nt] = __builtin_amdgcn_mfma_f32_16x16x32_bf16(pa, vb, O[nt], 0, 0, 0);
        }
    }

    #pragma unroll
    for (int nt = 0; nt < 4; nt++) {
        const int d = nt * 16 + fm;
        #pragma unroll
        for (int reg = 0; reg < 4; reg++) {
            const int i = iq0 + reg;
            attnb[(size_t)(brow0 + S0w + i) * 1024 + h * 64 + d] = f2bf(O[nt][reg] * inv[reg]);
        }
    }
}

// ---------------------------------------------------------------------------
// Fused (residual + 2 or 4 bf16 K-slice partials + column bias) + LayerNorm.
// ---------------------------------------------------------------------------
__global__ __launch_bounds__(256)
void ln_fuse(const float* __restrict__ resf,
             const unsigned short* __restrict__ resb,
             const unsigned short* __restrict__ p0,
             const unsigned short* __restrict__ p1,
             const unsigned short* __restrict__ p2,
             const unsigned short* __restrict__ p3,
             const float* __restrict__ cbias,
             const float* __restrict__ gamma,
             const float* __restrict__ beta,
             float* __restrict__ outf,
             unsigned short* __restrict__ outb)
{
    const int wave = threadIdx.x >> 6;
    const int lane = threadIdx.x & 63;
    const int row = blockIdx.x * 4 + wave;
    const size_t base = (size_t)row * D_MODEL;

    float x[16];
    float sum = 0.0f, sq = 0.0f;
    #pragma unroll
    for (int i = 0; i < 4; i++) {
        const int c4 = lane + i * 64;
        ushort4 u0 = ((const ushort4*)(p0 + base))[c4];
        ushort4 u1 = ((const ushort4*)(p1 + base))[c4];
        float4 cb = ((const float4*)cbias)[c4];
        float4 va;
        if (resf) {
            va = ((const float4*)(resf + base))[c4];
        } else {
            ushort4 ua = ((const ushort4*)(resb + base))[c4];
            va.x = bf2f(ua.x); va.y = bf2f(ua.y); va.z = bf2f(ua.z); va.w = bf2f(ua.w);
        }
        float e0 = va.x + bf2f(u0.x) + bf2f(u1.x) + cb.x;
        float e1 = va.y + bf2f(u0.y) + bf2f(u1.y) + cb.y;
        float e2 = va.z + bf2f(u0.z) + bf2f(u1.z) + cb.z;
        float e3 = va.w + bf2f(u0.w) + bf2f(u1.w) + cb.w;
        if (p2) {
            ushort4 u2 = ((const ushort4*)(p2 + base))[c4];
            ushort4 u3 = ((const ushort4*)(p3 + base))[c4];
            e0 += bf2f(u2.x) + bf2f(u3.x);
            e1 += bf2f(u2.y) + bf2f(u3.y);
            e2 += bf2f(u2.z) + bf2f(u3.z);
            e3 += bf2f(u2.w) + bf2f(u3.w);
        }
        x[i*4+0] = e0; x[i*4+1] = e1; x[i*4+2] = e2; x[i*4+3] = e3;
        sum += e0 + e1 + e2 + e3;
        sq  += e0*e0 + e1*e1 + e2*e2 + e3*e3;
    }
    #pragma unroll
    for (int off = 32; off > 0; off >>= 1) {
        sum += __shfl_xor(sum, off);
        sq  += __shfl_xor(sq,  off);
    }
    const float mean = sum * (1.0f / 1024.0f);
    const float var  = sq  * (1.0f / 1024.0f) - mean * mean;
    const float rs   = rsqrtf(var + 1e-5f);

    #pragma unroll
    for (int i = 0; i < 4; i++) {
        const int c4 = lane + i * 64;
        float4 g4 = ((const float4*)gamma)[c4];
        float4 b4 = ((const float4*)beta)[c4];
        float4 o;
        o.x = (x[i*4+0] - mean) * rs * g4.x + b4.x;
        o.y = (x[i*4+1] - mean) * rs * g4.y + b4.y;
        o.z = (x[i*4+2] - mean) * rs * g4.z + b4.z;
        o.w = (x[i*4+3] - mean) * rs * g4.w + b4.w;
        if (outf) ((float4*)(outf + base))[c4] = o;
        if (outb) {
            ushort4 u;
            u.x = f2bf(o.x); u.y = f2bf(o.y); u.z = f2bf(o.z); u.w = f2bf(o.w);
            ((ushort4*)(outb + base))[c4] = u;
        }
    }
}

// ---------------------------------------------------------------------------
extern "C" void kernel_launch(void* const* d_in, const int* in_sizes, int n_in,
                              void* d_out, int out_size, void* d_ws, size_t ws_size,
                              hipStream_t stream)
{
    const float* src = (const float*)d_in[0];
    const float* wq  = (const float*)d_in[1];
    const float* bq  = (const float*)d_in[2];
    const float* wk  = (const float*)d_in[3];
    const float* bk  = (const float*)d_in[4];
    const float* wv  = (const float*)d_in[5];
    const float* bv  = (const float*)d_in[6];
    const float* wo  = (const float*)d_in[7];
    const float* bo  = (const float*)d_in[8];
    const float* rel = (const float*)d_in[9];
    const float* w1  = (const float*)d_in[10];
    const float* b1  = (const float*)d_in[11];
    const float* w2  = (const float*)d_in[12];
    const float* b2  = (const float*)d_in[13];
    const float* g1  = (const float*)d_in[14];
    const float* be1 = (const float*)d_in[15];
    const float* g2  = (const float*)d_in[16];
    const float* be2 = (const float*)d_in[17];
    float* out = (float*)d_out;

    char* ws = (char*)d_ws;
    const size_t MB = 1048576;
    // Layout (peak 89 MB):
    //  0..6   wqkvb        (dead after QKV)   | reused by FF2 partial 0
    //  6..8   wob          (dead after WO)    |
    //  8..16  w1b          (dead after FF1)   | reused by FF2 partial 1
    // 16..24  w2b          (live through FF2)
    // 24..25  bqkv         (dead after QKV)
    // 25..33  xb / attnb   (dead after WO)
    // 33..57  qkvb         (dead after attn)
    // 33..49  WO partials 0,1 (dead after ln1)
    // 49..57  x1b          (live through ln2)
    // 57..89  ff1b         (live through FF2)
    unsigned short* wqkvb = (unsigned short*)(ws + 0);
    unsigned short* wob   = (unsigned short*)(ws + 6  * MB);
    unsigned short* w1b   = (unsigned short*)(ws + 8  * MB);
    unsigned short* w2b   = (unsigned short*)(ws + 16 * MB);
    float*          bqkv  = (float*)         (ws + 24 * MB);
    unsigned short* xb    = (unsigned short*)(ws + 25 * MB);
    unsigned short* attnb = xb;
    unsigned short* qkvb  = (unsigned short*)(ws + 33 * MB);
    unsigned short* z01   = (unsigned short*)(ws + 33 * MB);
    unsigned short* x1b   = (unsigned short*)(ws + 49 * MB);
    unsigned short* ff1b  = (unsigned short*)(ws + 57 * MB);
    unsigned short* f01   = (unsigned short*)(ws + 0);        // FF2 slices 0,1
    const size_t SL = (size_t)NROWS * 1024;   // 8 MB slice (ushort elems)

    const dim3 blk(256);
    cvt_all<<<16385, blk, 0, stream>>>(src, wq, wk, wv, wo, w1, w2, bq, bk, bv,
                                       xb, wqkvb, wob, w1b, w2b, bqkv);
    // QKV: 4096x3072, K=1024 (T=384, 16x24 tiles of 256x128)
    gemm_dp<<<384, blk, 0, stream>>>(xb, wqkvb, bqkv, qkvb, 1024, 1024, 384, 24,
                                     3072, 0, 0, 0);
    attn_mfma<<<1024, blk, 0, stream>>>(qkvb, rel, attnb);
    // WO: 4096x1024, K=1024 split 2 -> bf16 partials at {33,41} MB
    gemm_dp<<<256, blk, 0, stream>>>(attnb, wob, nullptr, z01, 1024, 512, 128, 8,
                                     1024, 0, SL, 0);
    // x1 = LN(src + z0 + z1 + bo)
    ln_fuse<<<NROWS / 4, blk, 0, stream>>>(src, nullptr, z01, z01 + SL,
                                           nullptr, nullptr,
                                           bo, g1, be1, nullptr, x1b);
    // FF1: 4096x4096, K=1024, relu+bias (T=512, 16x32 tiles of 256x128)
    gemm_dp<<<512, blk, 0, stream>>>(x1b, w1b, b1, ff1b, 1024, 1024, 512, 32,
                                     4096, 1, 0, 0);
    // FF2: 4096x1024, K=4096 split 2 -> bf16 partials at {0, 8} MB
    gemm_dp<<<256, blk, 0, stream>>>(ff1b, w2b, nullptr, f01, 4096, 2048, 128, 8,
                                     1024, 0, SL, 0);
    // out = LN(x1 + f0 + f1 + b2)
    ln_fuse<<<NROWS / 4, blk, 0, stream>>>(nullptr, x1b, f01, f01 + SL,
                                           nullptr, nullptr,
                                           b2, g2, be2, out, nullptr);
}

// Round 7
// 305.807 us; speedup vs baseline: 1.0507x; 1.0507x over previous
//
#include <hip/hip_runtime.h>

// ============================================================================
// ETC layer: windowed rel-pos attention + FFN, bf16 MFMA GEMMs on gfx950
//   B=2 S=2048 D_MODEL=1024 NHEAD=16 DHEAD=64 DFF=4096 R=25 W=51 K=5
// R15: best-of-both. R13 total == R12 total despite QKV +12us (gemm8p at
//   grid 192 underfilled 256 CUs) => gemm8p was >=11us faster combined on
//   WO/FF1/FF2 at grid 256 (full fill, 1 blk/CU). R14 showed grid 256 with
//   gemm_dp (4 waves/CU) regresses, so: QKV -> gemm_dp grid 384 (R12,
//   <=47us), WO/FF1/FF2 -> gemm8p grid 256 (R13). Both kernels verbatim
//   from passing rounds; ln_fuse reads 4 partials for WO and FF2.
// ============================================================================

#define D_MODEL 1024
#define SEQ     2048
#define NROWS   4096      // B*S
#define WIN     51
#define RAD     25

typedef __attribute__((ext_vector_type(8))) __bf16 bf16x8;
typedef __attribute__((ext_vector_type(4))) float  floatx4;

__device__ __forceinline__ unsigned short f2bf(float x) {
    unsigned u = __float_as_uint(x);
    unsigned r = u + 0x7fffu + ((u >> 16) & 1u);
    return (unsigned short)(r >> 16);
}
__device__ __forceinline__ float bf2f(unsigned short h) {
    return __uint_as_float(((unsigned)h) << 16);
}

// async global->LDS 16B per lane; LDS dest = wave-uniform base + lane*16
__device__ __forceinline__ void gld16(const unsigned short* g, unsigned short* l) {
    __builtin_amdgcn_global_load_lds(
        (const __attribute__((address_space(1))) unsigned int*)g,
        (__attribute__((address_space(3))) unsigned int*)l,
        16, 0, 0);
}

// ---------------------------------------------------------------------------
// One-shot conversion kernel (unchanged).
// ---------------------------------------------------------------------------
__device__ __forceinline__ void cvtgrp(const float* __restrict__ in,
                                       unsigned short* __restrict__ out, int g) {
    float4 f = ((const float4*)in)[g];
    ushort4 u;
    u.x = f2bf(f.x); u.y = f2bf(f.y); u.z = f2bf(f.z); u.w = f2bf(f.w);
    ((ushort4*)out)[g] = u;
}

__global__ __launch_bounds__(256)
void cvt_all(const float* __restrict__ src,
             const float* __restrict__ wq, const float* __restrict__ wk,
             const float* __restrict__ wv, const float* __restrict__ wo,
             const float* __restrict__ w1, const float* __restrict__ w2,
             const float* __restrict__ bq, const float* __restrict__ bk,
             const float* __restrict__ bv,
             unsigned short* __restrict__ xb,
             unsigned short* __restrict__ wqkvb,
             unsigned short* __restrict__ wob,
             unsigned short* __restrict__ w1b,
             unsigned short* __restrict__ w2b,
             float* __restrict__ bqkv)
{
    int g = blockIdx.x * 256 + threadIdx.x;
    if (g >= 4194496) return;
    if (g < 1048576) { cvtgrp(src, xb, g); return; }
    g -= 1048576;
    if (g < 262144) { cvtgrp(wq, wqkvb, g); return; }
    g -= 262144;
    if (g < 262144) { cvtgrp(wk, wqkvb + 1048576, g); return; }
    g -= 262144;
    if (g < 262144) { cvtgrp(wv, wqkvb + 2097152, g); return; }
    g -= 262144;
    if (g < 262144) { cvtgrp(wo, wob, g); return; }
    g -= 262144;
    if (g < 1048576) { cvtgrp(w1, w1b, g); return; }
    g -= 1048576;
    if (g < 1048576) { cvtgrp(w2, w2b, g); return; }
    g -= 1048576;
    float4 f = (g < 64) ? ((const float4*)bq)[g]
             : (g < 128) ? ((const float4*)bk)[g - 64]
                         : ((const float4*)bv)[g - 128];
    ((float4*)bqkv)[g] = f;
}

// ---------------------------------------------------------------------------
// gemm_dp (QKV): 256x128 tile, BK=32, 256 thr (4 waves 2Mx2N; 128x64/wave).
// Triple-buffered 72KB LDS, depth-2 prefetch, counted vmcnt(6) certify,
// chunk-XOR swizzle. Verbatim from R12 (passed, <=47us on all GEMMs).
// ---------------------------------------------------------------------------
__global__ __launch_bounds__(256, 2)
void gemm_dp(const unsigned short* __restrict__ A,
             const unsigned short* __restrict__ Wt,
             const float* __restrict__ bias,
             unsigned short* __restrict__ Cb,
             int kstride, int kloop, int T, int tncnt,
             int ldc, int relu, size_t sstep1, size_t sstep2)
{
    __shared__ __attribute__((aligned(16))) unsigned short AS[3 * 8192];
    __shared__ __attribute__((aligned(16))) unsigned short BS[3 * 4096];

    const int id = blockIdx.x;
    const int s  = id / T;
    const int t0 = id - s * T;
    const int sid = (t0 & 7) * (T >> 3) + (t0 >> 3);   // XCD-contiguous
    const int bm = (sid / tncnt) * 256;
    const int bn = (sid % tncnt) * 128;

    const int tid  = threadIdx.x;
    const int lane = tid & 63;
    const int wave = tid >> 6;
    const int wr   = wave >> 1;          // 0..1
    const int wc   = wave & 1;           // 0..1
    const int fm   = lane & 15;
    const int fq   = lane >> 4;

    const int kofs = s * kloop;
    const int NT   = kloop >> 5;         // BK=32 tiles

    const int ks  = (tid >> 3) & 7;
    const int gi  = tid ^ ks;            // 0..255
    const int r0s = gi >> 2;             // global row 0..63 (issue 0)
    const int c2s = gi & 3;              // global 16B chunk in row
    const unsigned short* Agp = A  + (size_t)(bm + r0s) * kstride + kofs + c2s * 8;
    const unsigned short* Wgp = Wt + (size_t)(bn + r0s) * kstride + kofs + c2s * 8;
    const size_t istep = (size_t)64 * kstride;   // +64 rows per issue

    const int rA  = wr * 128 + fm;
    const int rB  = wc * 64  + fm;
    const int c0A = ((((rA << 2) | fq) ^ (fm >> 1)) << 3);
    const int c0B = ((((rB << 2) | fq) ^ (fm >> 1)) << 3);

    // ---- prologue: stage tiles 0 (buf0) and 1 (buf1) ----
    {
        const unsigned short* Ap = Agp;
        const unsigned short* Wp = Wgp;
        gld16(Ap,             AS + tid * 8);
        gld16(Ap + istep,     AS + tid * 8 + 2048);
        gld16(Ap + 2 * istep, AS + tid * 8 + 4096);
        gld16(Ap + 3 * istep, AS + tid * 8 + 6144);
        gld16(Wp,             BS + tid * 8);
        gld16(Wp + istep,     BS + tid * 8 + 2048);
        Ap += 32; Wp += 32;
        gld16(Ap,             AS + 8192 + tid * 8);
        gld16(Ap + istep,     AS + 8192 + tid * 8 + 2048);
        gld16(Ap + 2 * istep, AS + 8192 + tid * 8 + 4096);
        gld16(Ap + 3 * istep, AS + 8192 + tid * 8 + 6144);
        gld16(Wp,             BS + 4096 + tid * 8);
        gld16(Wp + istep,     BS + 4096 + tid * 8 + 2048);
    }
    asm volatile("s_waitcnt vmcnt(6)" ::: "memory");   // tile 0 resident
    __builtin_amdgcn_sched_barrier(0);
    __builtin_amdgcn_s_barrier();
    __builtin_amdgcn_sched_barrier(0);

    floatx4 acc[8][4] = {};
    const unsigned short* Aga = Agp + 64;   // stages tile t+2
    const unsigned short* Wga = Wgp + 64;
    int cbA = 0, cbB = 0;                   // compute buf offsets (t%3)
    int pbA = 16384, pbB = 8192;            // prefetch buf offsets ((t+2)%3)

    for (int t = 0; t < NT; t++) {
        const bool pf = (t + 2 < NT);

        bf16x8 af[8], bf[4];
        #pragma unroll
        for (int mi = 0; mi < 8; mi++)
            af[mi] = *(const bf16x8*)(AS + cbA + c0A + mi * 512);
        #pragma unroll
        for (int ni = 0; ni < 4; ni++)
            bf[ni] = *(const bf16x8*)(BS + cbB + c0B + ni * 512);

        if (pf) {   // stage tile t+2: A x4, B x2 (FIFO order matters)
            gld16(Aga,             AS + pbA + tid * 8);
            gld16(Aga + istep,     AS + pbA + tid * 8 + 2048);
            gld16(Aga + 2 * istep, AS + pbA + tid * 8 + 4096);
            gld16(Aga + 3 * istep, AS + pbA + tid * 8 + 6144);
            gld16(Wga,             BS + pbB + tid * 8);
            gld16(Wga + istep,     BS + pbB + tid * 8 + 2048);
        }

        __builtin_amdgcn_s_setprio(1);
        #pragma unroll
        for (int mi = 0; mi < 8; mi++)
            #pragma unroll
            for (int ni = 0; ni < 4; ni++)
                acc[mi][ni] = __builtin_amdgcn_mfma_f32_16x16x32_bf16(
                    af[mi], bf[ni], acc[mi][ni], 0, 0, 0);
        __builtin_amdgcn_s_setprio(0);

        if (t + 1 < NT) {
            if (pf) asm volatile("s_waitcnt vmcnt(6)" ::: "memory");
            else    asm volatile("s_waitcnt vmcnt(0)" ::: "memory");
            __builtin_amdgcn_sched_barrier(0);
            __builtin_amdgcn_s_barrier();
            __builtin_amdgcn_sched_barrier(0);
        }
        cbA = (cbA == 16384) ? 0 : cbA + 8192;
        cbB = (cbB == 8192)  ? 0 : cbB + 4096;
        pbA = (pbA == 16384) ? 0 : pbA + 8192;
        pbB = (pbB == 8192)  ? 0 : pbB + 4096;
        Aga += 32;
        Wga += 32;
    }

    // ---- epilogue ----
    unsigned short* Co = Cb + (size_t)(s & 1) * sstep1 + (size_t)(s >> 1) * sstep2;
    const int r0  = bm + wr * 128 + fq * 4;
    const int c0e = bn + wc * 64 + fm;
    #pragma unroll
    for (int mi = 0; mi < 8; mi++) {
        #pragma unroll
        for (int ni = 0; ni < 4; ni++) {
            const int col = c0e + ni * 16;
            const float bv = bias ? bias[col] : 0.0f;
            #pragma unroll
            for (int rr = 0; rr < 4; rr++) {
                const int row = r0 + mi * 16 + rr;
                float v = acc[mi][ni][rr] + bv;
                if (relu) v = fmaxf(v, 0.0f);
                Co[(size_t)row * ldc + col] = f2bf(v);
            }
        }
    }
}

// ---------------------------------------------------------------------------
// gemm8p (WO/FF1/FF2): 256x256 tile, BK=64, 512 thr (8 waves 2Mx4N),
// 128KB LDS dbuf, 8-phase schedule, counted vmcnt(4) at phases 4/8.
// Verbatim from R13 (passed; faster than gemm_dp at grid 256 full fill).
// ---------------------------------------------------------------------------
__global__ __launch_bounds__(512, 2)
void gemm8p(const unsigned short* __restrict__ A,
            const unsigned short* __restrict__ Wt,
            const float* __restrict__ bias,
            unsigned short* __restrict__ Cb,
            int kstride, int kloop, int T, int tncnt,
            int ldc, int relu, size_t sstep1, size_t sstep2)
{
    __shared__ __attribute__((aligned(16))) unsigned short AS[2 * 16384];
    __shared__ __attribute__((aligned(16))) unsigned short BS[2 * 16384];

    const int id = blockIdx.x;
    const int sl = id / T;               // split-K slice
    const int t0 = id - sl * T;
    const int sid = (t0 & 7) * (T >> 3) + (t0 >> 3);   // XCD-contiguous
    const int bm = (sid / tncnt) * 256;
    const int bn = (sid % tncnt) * 256;

    const int tid  = threadIdx.x;
    const int lane = tid & 63;
    const int wave = tid >> 6;
    const int wr   = wave >> 2;          // 0..1  (M half)
    const int wc   = wave & 3;           // 0..3  (N quarter)
    const int fm   = lane & 15;
    const int fq   = lane >> 4;

    const int kofs  = sl * kloop;
    const int NITER = kloop >> 7;        // 2 K-tiles (BK=64) per iteration

    const int srow = tid >> 3;                          // 0..63
    const int scol = ((tid & 7) ^ ((tid >> 3) & 7)) * 8;
    const unsigned short* PA = A  + (size_t)(bm + srow) * kstride + kofs + scol;
    const unsigned short* PW = Wt + (size_t)(bn + srow) * kstride + kofs + scol;
    const size_t rs64 = (size_t)64 * kstride;           // +64 rows

    const int aoff = (wr * 128 + fm) * 64;
    const int boff = (wc * 64  + fm) * 64;
    const int ck0  = (fq ^ (fm & 7)) * 8;               // ks=0 chunk
    const int ck1  = ck0 ^ 32;                          // ks=1 chunk (c^4)

    floatx4 acc[8][4] = {};

    auto STG = [&](const unsigned short* g, int h, unsigned short* l) {
        gld16(g + (size_t)(2 * h)     * rs64, l + h * 8192 + tid * 8);
        gld16(g + (size_t)(2 * h + 1) * rs64, l + h * 8192 + 4096 + tid * 8);
    };
    auto rdA = [&](bf16x8 (&d)[4][2], int bufb, int mb) {
        #pragma unroll
        for (int mi = 0; mi < 4; mi++) {
            d[mi][0] = *(const bf16x8*)(AS + bufb + aoff + (mb + mi) * 1024 + ck0);
            d[mi][1] = *(const bf16x8*)(AS + bufb + aoff + (mb + mi) * 1024 + ck1);
        }
    };
    auto rdB = [&](bf16x8 (&d)[2][2], int bufb, int nb) {
        #pragma unroll
        for (int ni = 0; ni < 2; ni++) {
            d[ni][0] = *(const bf16x8*)(BS + bufb + boff + (nb + ni) * 1024 + ck0);
            d[ni][1] = *(const bf16x8*)(BS + bufb + boff + (nb + ni) * 1024 + ck1);
        }
    };
    auto mmq = [&](bf16x8 (&a)[4][2], bf16x8 (&b)[2][2], int mb, int nb) {
        __builtin_amdgcn_s_setprio(1);
        #pragma unroll
        for (int ks = 0; ks < 2; ks++)
            #pragma unroll
            for (int mi = 0; mi < 4; mi++)
                #pragma unroll
                for (int ni = 0; ni < 2; ni++)
                    acc[mb + mi][nb + ni] = __builtin_amdgcn_mfma_f32_16x16x32_bf16(
                        a[mi][ks], b[ni][ks], acc[mb + mi][nb + ni], 0, 0, 0);
        __builtin_amdgcn_s_setprio(0);
    };
    auto barpre = [&]() {
        __builtin_amdgcn_sched_barrier(0);
        __builtin_amdgcn_s_barrier();
        asm volatile("s_waitcnt lgkmcnt(0)" ::: "memory");
        __builtin_amdgcn_sched_barrier(0);
    };
    auto barpost = [&]() {
        __builtin_amdgcn_sched_barrier(0);
        __builtin_amdgcn_s_barrier();
        __builtin_amdgcn_sched_barrier(0);
    };

    unsigned short* AS0 = AS;            unsigned short* AS1 = AS + 16384;
    unsigned short* BS0 = BS;            unsigned short* BS1 = BS + 16384;

    // ---- prologue ----
    STG(PA, 0, AS0); STG(PA, 1, AS0);
    STG(PW, 0, BS0); STG(PW, 1, BS0);
    STG(PW + 64, 0, BS1); STG(PW + 64, 1, BS1);
    __builtin_amdgcn_sched_barrier(0);
    asm volatile("s_waitcnt vmcnt(4)" ::: "memory");
    __builtin_amdgcn_sched_barrier(0);
    __builtin_amdgcn_s_barrier();
    __builtin_amdgcn_sched_barrier(0);

    for (int it = 0; it < NITER; it++) {
        const bool more = (it + 1 < NITER);
        bf16x8 a03[4][2], a47[4][2], b01[2][2], b23[2][2];

        // -- p1 --
        rdA(a03, 0, 0); rdB(b01, 0, 0);
        STG(PA + 64, 0, AS1);                 // A[s+1] h0
        barpre(); mmq(a03, b01, 0, 0); barpost();
        // -- p2 --
        rdB(b23, 0, 2);
        STG(PA + 64, 1, AS1);                 // A[s+1] h1
        barpre(); mmq(a03, b23, 0, 2); barpost();
        // -- p3 --
        rdA(a47, 0, 4);
        if (more) STG(PW + 128, 0, BS0);      // B[s+2] h0
        barpre(); mmq(a47, b01, 4, 0); barpost();
        // -- p4 + certify --
        if (more) STG(PW + 128, 1, BS0);      // B[s+2] h1
        __builtin_amdgcn_sched_barrier(0);
        if (more) asm volatile("s_waitcnt vmcnt(4)" ::: "memory");
        else      asm volatile("s_waitcnt vmcnt(0)" ::: "memory");
        __builtin_amdgcn_sched_barrier(0);
        __builtin_amdgcn_s_barrier();
        __builtin_amdgcn_sched_barrier(0);
        mmq(a47, b23, 4, 2); barpost();
        // -- p5 --
        rdA(a03, 16384, 0); rdB(b01, 16384, 0);
        if (more) STG(PA + 128, 0, AS0);      // A[s+2] h0
        barpre(); mmq(a03, b01, 0, 0); barpost();
        // -- p6 --
        rdB(b23, 16384, 2);
        if (more) STG(PA + 128, 1, AS0);      // A[s+2] h1
        barpre(); mmq(a03, b23, 0, 2); barpost();
        // -- p7 --
        rdA(a47, 16384, 4);
        if (more) STG(PW + 192, 0, BS1);      // B[s+3] h0
        barpre(); mmq(a47, b01, 4, 0); barpost();
        // -- p8 + certify --
        if (more) {
            STG(PW + 192, 1, BS1);            // B[s+3] h1
            __builtin_amdgcn_sched_barrier(0);
            asm volatile("s_waitcnt vmcnt(4)" ::: "memory");
        }
        __builtin_amdgcn_sched_barrier(0);
        __builtin_amdgcn_s_barrier();
        __builtin_amdgcn_sched_barrier(0);
        mmq(a47, b23, 4, 2); barpost();

        PA += 128; PW += 128;
    }

    // ---- epilogue ----
    unsigned short* Co = Cb + (size_t)(sl & 1) * sstep1 + (size_t)(sl >> 1) * sstep2;
    const int r0  = bm + wr * 128 + fq * 4;
    const int c0e = bn + wc * 64 + fm;
    #pragma unroll
    for (int mi = 0; mi < 8; mi++) {
        #pragma unroll
        for (int ni = 0; ni < 4; ni++) {
            const int col = c0e + ni * 16;
            const float bv = bias ? bias[col] : 0.0f;
            #pragma unroll
            for (int rr = 0; rr < 4; rr++) {
                const int row = r0 + mi * 16 + rr;
                float v = acc[mi][ni][rr] + bv;
                if (relu) v = fmaxf(v, 0.0f);
                Co[(size_t)row * ldc + col] = f2bf(v);
            }
        }
    }
}

// ---------------------------------------------------------------------------
// Banded MFMA windowed attention (unchanged).
// ---------------------------------------------------------------------------
__global__ __launch_bounds__(256, 2)
void attn_mfma(const unsigned short* __restrict__ qkv,
               const float* __restrict__ rel,
               unsigned short* __restrict__ attnb)
{
    __shared__ __attribute__((aligned(16))) unsigned short Qs[64 * 72];
    __shared__ __attribute__((aligned(16))) unsigned short Ks[128 * 72];
    __shared__ __attribute__((aligned(16))) unsigned short Vt[64 * 168];
    __shared__ __attribute__((aligned(16))) unsigned short Rs[16 * 72];
    __shared__ __attribute__((aligned(16))) unsigned short Pl[4 * 16 * 104];
    __shared__ float Qrl[4 * 16 * 12];

    const int t   = threadIdx.x;
    const int blk = blockIdx.x;
    const int st  = blk & 31;
    const int h   = (blk >> 5) & 15;
    const int b   = blk >> 9;
    const int s0  = st << 6;
    const int brow0 = b * SEQ;

    const int trow = t >> 3;
    const int tc   = (t & 7) * 8;
    const uint4 z4 = make_uint4(0, 0, 0, 0);

    #pragma unroll
    for (int p = 0; p < 2; p++) {
        int r = trow + p * 32;
        uint4 v = *(const uint4*)(qkv + (size_t)(brow0 + s0 + r) * 3072 + h * 64 + tc);
        *(uint4*)(Qs + r * 72 + tc) = v;
    }
    #pragma unroll
    for (int p = 0; p < 4; p++) {
        int kr = trow + p * 32;
        int ka = s0 - 25 + kr;
        bool in = (ka >= 0) & (ka < SEQ);
        uint4 kv = z4, vv = z4;
        if (in) {
            kv = *(const uint4*)(qkv + (size_t)(brow0 + ka) * 3072 + 1024 + h * 64 + tc);
            vv = *(const uint4*)(qkv + (size_t)(brow0 + ka) * 3072 + 2048 + h * 64 + tc);
        }
        *(uint4*)(Ks + kr * 72 + tc) = kv;
        const unsigned short* e = (const unsigned short*)&vv;
        #pragma unroll
        for (int j = 0; j < 8; j++)
            Vt[(tc + j) * 168 + kr] = e[j];
    }
    if (t < 176) {
        float4 f = ((const float4*)rel)[t];
        int fi = t * 4, rr = fi >> 6, cc = fi & 63;
        ushort4 u;
        u.x = f2bf(f.x); u.y = f2bf(f.y); u.z = f2bf(f.z); u.w = f2bf(f.w);
        *(ushort4*)(Rs + rr * 72 + cc) = u;
    } else {
        int fi = 704 + (t - 176) * 4, rr = fi >> 6, cc = fi & 63;
        *(ushort4*)(Rs + rr * 72 + cc) = make_ushort4(0, 0, 0, 0);
    }
    {
        int n = t * 4, w2 = n >> 8, rem = n & 255, rr = rem >> 4, cc = 80 + (rem & 15);
        *(ushort4*)(Pl + w2 * (16 * 104) + rr * 104 + cc) = make_ushort4(0, 0, 0, 0);
    }
    for (int idx = t; idx < 320; idx += 256) {
        int r = idx / 5, cchunk = idx % 5;
        *(uint4*)(Vt + r * 168 + 128 + cchunk * 8) = z4;
    }
    __syncthreads();

    const int wave = t >> 6;
    const int lane = t & 63;
    const int fm   = lane & 15;
    const int fk8  = (lane >> 4) * 8;
    const int S0w  = s0 + wave * 16;
    unsigned short* Plw = Pl + wave * (16 * 104);
    float* Ql = Qrl + wave * (16 * 12);

    bf16x8 qa0 = *(const bf16x8*)(Qs + (wave * 16 + fm) * 72 + fk8);
    bf16x8 qa1 = *(const bf16x8*)(Qs + (wave * 16 + fm) * 72 + fk8 + 32);

    floatx4 Sc[5];
    #pragma unroll
    for (int nt = 0; nt < 5; nt++) {
        bf16x8 kb0 = *(const bf16x8*)(Ks + (wave * 16 + nt * 16 + fm) * 72 + fk8);
        bf16x8 kb1 = *(const bf16x8*)(Ks + (wave * 16 + nt * 16 + fm) * 72 + fk8 + 32);
        floatx4 acc = {0.f, 0.f, 0.f, 0.f};
        acc = __builtin_amdgcn_mfma_f32_16x16x32_bf16(qa0, kb0, acc, 0, 0, 0);
        acc = __builtin_amdgcn_mfma_f32_16x16x32_bf16(qa1, kb1, acc, 0, 0, 0);
        Sc[nt] = acc;
    }
    {
        bf16x8 rb0 = *(const bf16x8*)(Rs + fm * 72 + fk8);
        bf16x8 rb1 = *(const bf16x8*)(Rs + fm * 72 + fk8 + 32);
        floatx4 qr = {0.f, 0.f, 0.f, 0.f};
        qr = __builtin_amdgcn_mfma_f32_16x16x32_bf16(qa0, rb0, qr, 0, 0, 0);
        qr = __builtin_amdgcn_mfma_f32_16x16x32_bf16(qa1, rb1, qr, 0, 0, 0);
        if (fm < 12) {
            #pragma unroll
            for (int reg = 0; reg < 4; reg++)
                Ql[((lane >> 4) * 4 + reg) * 12 + fm] = qr[reg];
        }
    }

    float inv[4];
    const int iq0 = (lane >> 4) * 4;
    #pragma unroll
    for (int reg = 0; reg < 4; reg++) {
        const int i = iq0 + reg;
        float sc[5];
        float mx = -1e30f;
        #pragma unroll
        for (int nt = 0; nt < 5; nt++) {
            int c   = nt * 16 + fm;
            int off = c - 25 - i;
            int ka  = S0w - 25 + c;
            bool valid = (off >= -RAD) & (off <= RAD) & (ka >= 0) & (ka < SEQ);
            int rid = min(max(off, -5), 5) + 5;
            float v = valid ? (Sc[nt][reg] + Ql[i * 12 + rid]) * 0.125f : -1e30f;
            sc[nt] = v;
            mx = fmaxf(mx, v);
        }
        #pragma unroll
        for (int o = 1; o < 16; o <<= 1) mx = fmaxf(mx, __shfl_xor(mx, o));
        float sum = 0.f;
        #pragma unroll
        for (int nt = 0; nt < 5; nt++) {
            float e = __expf(sc[nt] - mx);
            sum += e;
            Plw[i * 104 + nt * 16 + fm] = f2bf(e);
        }
        #pragma unroll
        for (int o = 1; o < 16; o <<= 1) sum += __shfl_xor(sum, o);
        inv[reg] = 1.0f / sum;
    }

    floatx4 O[4] = {};
    #pragma unroll
    for (int kc = 0; kc < 3; kc++) {
        bf16x8 pa = *(const bf16x8*)(Plw + fm * 104 + fk8 + kc * 32);
        #pragma unroll
        for (int nt = 0; nt < 4; nt++) {
            bf16x8 vb = *(const bf16x8*)(Vt + (nt * 16 + fm) * 168 + wave * 16 + fk8 + kc * 32);
            O[nt] = __builtin_amdgcn_mfma_f32_16x16x32_bf16(pa, vb, O[nt], 0, 0, 0);
        }
    }

    #pragma unroll
    for (int nt = 0; nt < 4; nt++) {
        const int d = nt * 16 + fm;
        #pragma unroll
        for (int reg = 0; reg < 4; reg++) {
            const int i = iq0 + reg;
            attnb[(size_t)(brow0 + S0w + i) * 1024 + h * 64 + d] = f2bf(O[nt][reg] * inv[reg]);
        }
    }
}

// ---------------------------------------------------------------------------
// Fused (residual + 2 or 4 bf16 K-slice partials + column bias) + LayerNorm.
// ---------------------------------------------------------------------------
__global__ __launch_bounds__(256)
void ln_fuse(const float* __restrict__ resf,
             const unsigned short* __restrict__ resb,
             const unsigned short* __restrict__ p0,
             const unsigned short* __restrict__ p1,
             const unsigned short* __restrict__ p2,
             const unsigned short* __restrict__ p3,
             const float* __restrict__ cbias,
             const float* __restrict__ gamma,
             const float* __restrict__ beta,
             float* __restrict__ outf,
             unsigned short* __restrict__ outb)
{
    const int wave = threadIdx.x >> 6;
    const int lane = threadIdx.x & 63;
    const int row = blockIdx.x * 4 + wave;
    const size_t base = (size_t)row * D_MODEL;

    float x[16];
    float sum = 0.0f, sq = 0.0f;
    #pragma unroll
    for (int i = 0; i < 4; i++) {
        const int c4 = lane + i * 64;
        ushort4 u0 = ((const ushort4*)(p0 + base))[c4];
        ushort4 u1 = ((const ushort4*)(p1 + base))[c4];
        float4 cb = ((const float4*)cbias)[c4];
        float4 va;
        if (resf) {
            va = ((const float4*)(resf + base))[c4];
        } else {
            ushort4 ua = ((const ushort4*)(resb + base))[c4];
            va.x = bf2f(ua.x); va.y = bf2f(ua.y); va.z = bf2f(ua.z); va.w = bf2f(ua.w);
        }
        float e0 = va.x + bf2f(u0.x) + bf2f(u1.x) + cb.x;
        float e1 = va.y + bf2f(u0.y) + bf2f(u1.y) + cb.y;
        float e2 = va.z + bf2f(u0.z) + bf2f(u1.z) + cb.z;
        float e3 = va.w + bf2f(u0.w) + bf2f(u1.w) + cb.w;
        if (p2) {
            ushort4 u2 = ((const ushort4*)(p2 + base))[c4];
            ushort4 u3 = ((const ushort4*)(p3 + base))[c4];
            e0 += bf2f(u2.x) + bf2f(u3.x);
            e1 += bf2f(u2.y) + bf2f(u3.y);
            e2 += bf2f(u2.z) + bf2f(u3.z);
            e3 += bf2f(u2.w) + bf2f(u3.w);
        }
        x[i*4+0] = e0; x[i*4+1] = e1; x[i*4+2] = e2; x[i*4+3] = e3;
        sum += e0 + e1 + e2 + e3;
        sq  += e0*e0 + e1*e1 + e2*e2 + e3*e3;
    }
    #pragma unroll
    for (int off = 32; off > 0; off >>= 1) {
        sum += __shfl_xor(sum, off);
        sq  += __shfl_xor(sq,  off);
    }
    const float mean = sum * (1.0f / 1024.0f);
    const float var  = sq  * (1.0f / 1024.0f) - mean * mean;
    const float rs   = rsqrtf(var + 1e-5f);

    #pragma unroll
    for (int i = 0; i < 4; i++) {
        const int c4 = lane + i * 64;
        float4 g4 = ((const float4*)gamma)[c4];
        float4 b4 = ((const float4*)beta)[c4];
        float4 o;
        o.x = (x[i*4+0] - mean) * rs * g4.x + b4.x;
        o.y = (x[i*4+1] - mean) * rs * g4.y + b4.y;
        o.z = (x[i*4+2] - mean) * rs * g4.z + b4.z;
        o.w = (x[i*4+3] - mean) * rs * g4.w + b4.w;
        if (outf) ((float4*)(outf + base))[c4] = o;
        if (outb) {
            ushort4 u;
            u.x = f2bf(o.x); u.y = f2bf(o.y); u.z = f2bf(o.z); u.w = f2bf(o.w);
            ((ushort4*)(outb + base))[c4] = u;
        }
    }
}

// ---------------------------------------------------------------------------
extern "C" void kernel_launch(void* const* d_in, const int* in_sizes, int n_in,
                              void* d_out, int out_size, void* d_ws, size_t ws_size,
                              hipStream_t stream)
{
    const float* src = (const float*)d_in[0];
    const float* wq  = (const float*)d_in[1];
    const float* bq  = (const float*)d_in[2];
    const float* wk  = (const float*)d_in[3];
    const float* bk  = (const float*)d_in[4];
    const float* wv  = (const float*)d_in[5];
    const float* bv  = (const float*)d_in[6];
    const float* wo  = (const float*)d_in[7];
    const float* bo  = (const float*)d_in[8];
    const float* rel = (const float*)d_in[9];
    const float* w1  = (const float*)d_in[10];
    const float* b1  = (const float*)d_in[11];
    const float* w2  = (const float*)d_in[12];
    const float* b2  = (const float*)d_in[13];
    const float* g1  = (const float*)d_in[14];
    const float* be1 = (const float*)d_in[15];
    const float* g2  = (const float*)d_in[16];
    const float* be2 = (const float*)d_in[17];
    float* out = (float*)d_out;

    char* ws = (char*)d_ws;
    const size_t MB = 1048576;
    // Layout (peak 89 MB) — identical to R12/R13:
    //  0..6   wqkvb (dead after QKV) | reused by FF2 partials 0,1
    //  6..8   wob   (dead after WO)
    //  8..16  w1b   (dead after FF1)
    // 16..24  w2b   (live through FF2)
    // 24..25  bqkv  (dead after QKV) | reused by FF2 partials 2,3
    // 25..33  xb / attnb (dead after WO)
    // 33..57  qkvb  (dead after attn)
    // 33..49  WO partials 0,1 (dead after ln1)
    // 57..73  WO partials 2,3 (dead after ln1; inside ff1b, written later)
    // 49..57  x1b   (live through ln2)
    // 57..89  ff1b  (live through FF2)
    unsigned short* wqkvb = (unsigned short*)(ws + 0);
    unsigned short* wob   = (unsigned short*)(ws + 6  * MB);
    unsigned short* w1b   = (unsigned short*)(ws + 8  * MB);
    unsigned short* w2b   = (unsigned short*)(ws + 16 * MB);
    float*          bqkv  = (float*)         (ws + 24 * MB);
    unsigned short* xb    = (unsigned short*)(ws + 25 * MB);
    unsigned short* attnb = xb;
    unsigned short* qkvb  = (unsigned short*)(ws + 33 * MB);
    unsigned short* z01   = (unsigned short*)(ws + 33 * MB);
    unsigned short* x1b   = (unsigned short*)(ws + 49 * MB);
    unsigned short* ff1b  = (unsigned short*)(ws + 57 * MB);
    unsigned short* f01   = (unsigned short*)(ws + 0);        // FF2 slices 0,1
    const size_t SL    = (size_t)NROWS * 1024;   // 8 MB slice (ushort elems)
    const size_t SOFF2 = (size_t)12 * MB;        // ushort elems == 24 MB bytes

    const dim3 blk(256);
    const dim3 blk5(512);
    cvt_all<<<16385, blk, 0, stream>>>(src, wq, wk, wv, wo, w1, w2, bq, bk, bv,
                                       xb, wqkvb, wob, w1b, w2b, bqkv);
    // QKV: 4096x3072, K=1024 (gemm_dp, T=384, 16x24 tiles of 256x128)
    gemm_dp<<<384, blk, 0, stream>>>(xb, wqkvb, bqkv, qkvb, 1024, 1024, 384, 24,
                                     3072, 0, 0, 0);
    attn_mfma<<<1024, blk, 0, stream>>>(qkvb, rel, attnb);
    // WO: 4096x1024, K=1024 split 4 (gemm8p, grid 256) -> partials {33,41,57,65} MB
    gemm8p<<<256, blk5, 0, stream>>>(attnb, wob, nullptr, z01, 1024, 256, 64, 4,
                                     1024, 0, SL, SOFF2);
    // x1 = LN(src + z0 + z1 + z2 + z3 + bo)
    ln_fuse<<<NROWS / 4, blk, 0, stream>>>(src, nullptr, z01, z01 + SL,
                                           z01 + SOFF2, z01 + SOFF2 + SL,
                                           bo, g1, be1, nullptr, x1b);
    // FF1: 4096x4096, K=1024, relu+bias (gemm8p, grid 256, 16x16 tiles of 256^2)
    gemm8p<<<256, blk5, 0, stream>>>(x1b, w1b, b1, ff1b, 1024, 1024, 256, 16,
                                     4096, 1, 0, 0);
    // FF2: 4096x1024, K=4096 split 4 (gemm8p, grid 256) -> partials {0,8,24,32} MB
    gemm8p<<<256, blk5, 0, stream>>>(ff1b, w2b, nullptr, f01, 4096, 1024, 64, 4,
                                     1024, 0, SL, SOFF2);
    // out = LN(x1 + f0 + f1 + f2 + f3 + b2)
    ln_fuse<<<NROWS / 4, blk, 0, stream>>>(nullptr, x1b, f01, f01 + SL,
                                           f01 + SOFF2, f01 + SOFF2 + SL,
                                           b2, g2, be2, out, nullptr);
}

// Round 8
// 297.386 us; speedup vs baseline: 1.0804x; 1.0283x over previous
//
#include <hip/hip_runtime.h>

// ============================================================================
// ETC layer: windowed rel-pos attention + FFN, bf16 MFMA GEMMs on gfx950
//   B=2 S=2048 D_MODEL=1024 NHEAD=16 DHEAD=64 DFF=4096 R=25 W=51 K=5
// R16 = R15 + conversion split/fold:
//   - cvt1 converts only what QKV needs (src, wq/wk/wv, biases; 42 MB).
//   - wo/w1/w2 conversion (54 MB traffic) folded into the QKV launch as
//     9216 trailing converter blocks of qkv_cvt (gemm blocks 0..383 first,
//     converters fill idle BW behind them; kernel boundary publishes w*b
//     before WO/FF1/FF2 need them). Removes ~10us of serial BW work.
//   R15 structure kept: QKV = gemm_dp body (grid 384), WO/FF1/FF2 = gemm8p
//   grid 256 (split-K4 for WO/FF2), ln_fuse 4-partial reads.
// ============================================================================

#define D_MODEL 1024
#define SEQ     2048
#define NROWS   4096      // B*S
#define WIN     51
#define RAD     25

typedef __attribute__((ext_vector_type(8))) __bf16 bf16x8;
typedef __attribute__((ext_vector_type(4))) float  floatx4;

__device__ __forceinline__ unsigned short f2bf(float x) {
    unsigned u = __float_as_uint(x);
    unsigned r = u + 0x7fffu + ((u >> 16) & 1u);
    return (unsigned short)(r >> 16);
}
__device__ __forceinline__ float bf2f(unsigned short h) {
    return __uint_as_float(((unsigned)h) << 16);
}

// async global->LDS 16B per lane; LDS dest = wave-uniform base + lane*16
__device__ __forceinline__ void gld16(const unsigned short* g, unsigned short* l) {
    __builtin_amdgcn_global_load_lds(
        (const __attribute__((address_space(1))) unsigned int*)g,
        (__attribute__((address_space(3))) unsigned int*)l,
        16, 0, 0);
}

__device__ __forceinline__ void cvtgrp(const float* __restrict__ in,
                                       unsigned short* __restrict__ out, int g) {
    float4 f = ((const float4*)in)[g];
    ushort4 u;
    u.x = f2bf(f.x); u.y = f2bf(f.y); u.z = f2bf(f.z); u.w = f2bf(f.w);
    ((ushort4*)out)[g] = u;
}

// ---------------------------------------------------------------------------
// cvt1: only what QKV needs — src, wq, wk, wv, biases. 1835200 groups.
// ---------------------------------------------------------------------------
__global__ __launch_bounds__(256)
void cvt1(const float* __restrict__ src,
          const float* __restrict__ wq, const float* __restrict__ wk,
          const float* __restrict__ wv,
          const float* __restrict__ bq, const float* __restrict__ bk,
          const float* __restrict__ bv,
          unsigned short* __restrict__ xb,
          unsigned short* __restrict__ wqkvb,
          float* __restrict__ bqkv)
{
    int g = blockIdx.x * 256 + threadIdx.x;
    if (g >= 1835200) return;
    if (g < 1048576) { cvtgrp(src, xb, g); return; }
    g -= 1048576;
    if (g < 262144) { cvtgrp(wq, wqkvb, g); return; }
    g -= 262144;
    if (g < 262144) { cvtgrp(wk, wqkvb + 1048576, g); return; }
    g -= 262144;
    if (g < 262144) { cvtgrp(wv, wqkvb + 2097152, g); return; }
    g -= 262144;
    float4 f = (g < 64) ? ((const float4*)bq)[g]
             : (g < 128) ? ((const float4*)bk)[g - 64]
                         : ((const float4*)bv)[g - 128];
    ((float4*)bqkv)[g] = f;
}

// ---------------------------------------------------------------------------
// qkv_cvt: blocks 0..383 = QKV GEMM (gemm_dp body, 256x128 tile, BK=32,
//   4 waves, triple-buffered 72KB LDS, depth-2 prefetch, vmcnt(6) certify,
//   chunk-XOR swizzle — verbatim from R12/R15 which passed).
// blocks 384..9599 = convert wo (262144 gr), w1 (1048576), w2 (1048576)
//   to bf16 behind the GEMM (needed only by later launches).
// ---------------------------------------------------------------------------
__global__ __launch_bounds__(256, 2)
void qkv_cvt(const unsigned short* __restrict__ A,    // xb
             const unsigned short* __restrict__ Wt,   // wqkvb
             const float* __restrict__ bias,          // bqkv
             unsigned short* __restrict__ Cb,         // qkvb
             const float* __restrict__ wo, const float* __restrict__ w1,
             const float* __restrict__ w2,
             unsigned short* __restrict__ wob,
             unsigned short* __restrict__ w1b,
             unsigned short* __restrict__ w2b)
{
    __shared__ __attribute__((aligned(16))) unsigned short AS[3 * 8192];
    __shared__ __attribute__((aligned(16))) unsigned short BS[3 * 4096];

    if (blockIdx.x >= 384) {   // ---- converter blocks ----
        int g = (blockIdx.x - 384) * 256 + threadIdx.x;
        if (g < 262144) { cvtgrp(wo, wob, g); return; }
        g -= 262144;
        if (g < 1048576) { cvtgrp(w1, w1b, g); return; }
        g -= 1048576;
        cvtgrp(w2, w2b, g);
        return;
    }

    // ---- QKV GEMM: M=4096 N=3072 K=1024, ldc=3072, T=384, tncnt=24 ----
    const int t0 = blockIdx.x;
    const int sid = (t0 & 7) * 48 + (t0 >> 3);   // XCD-contiguous, T>>3=48
    const int bm = (sid / 24) * 256;
    const int bn = (sid % 24) * 128;

    const int tid  = threadIdx.x;
    const int lane = tid & 63;
    const int wave = tid >> 6;
    const int wr   = wave >> 1;          // 0..1
    const int wc   = wave & 1;           // 0..1
    const int fm   = lane & 15;
    const int fq   = lane >> 4;

    const int NT = 32;                   // K=1024, BK=32

    const int ks  = (tid >> 3) & 7;
    const int gi  = tid ^ ks;            // 0..255
    const int r0s = gi >> 2;             // global row 0..63 (issue 0)
    const int c2s = gi & 3;              // global 16B chunk in row
    const unsigned short* Agp = A  + (size_t)(bm + r0s) * 1024 + c2s * 8;
    const unsigned short* Wgp = Wt + (size_t)(bn + r0s) * 1024 + c2s * 8;
    const size_t istep = (size_t)64 * 1024;   // +64 rows per issue

    const int rA  = wr * 128 + fm;
    const int rB  = wc * 64  + fm;
    const int c0A = ((((rA << 2) | fq) ^ (fm >> 1)) << 3);
    const int c0B = ((((rB << 2) | fq) ^ (fm >> 1)) << 3);

    // ---- prologue: stage tiles 0 (buf0) and 1 (buf1) ----
    {
        const unsigned short* Ap = Agp;
        const unsigned short* Wp = Wgp;
        gld16(Ap,             AS + tid * 8);
        gld16(Ap + istep,     AS + tid * 8 + 2048);
        gld16(Ap + 2 * istep, AS + tid * 8 + 4096);
        gld16(Ap + 3 * istep, AS + tid * 8 + 6144);
        gld16(Wp,             BS + tid * 8);
        gld16(Wp + istep,     BS + tid * 8 + 2048);
        Ap += 32; Wp += 32;
        gld16(Ap,             AS + 8192 + tid * 8);
        gld16(Ap + istep,     AS + 8192 + tid * 8 + 2048);
        gld16(Ap + 2 * istep, AS + 8192 + tid * 8 + 4096);
        gld16(Ap + 3 * istep, AS + 8192 + tid * 8 + 6144);
        gld16(Wp,             BS + 4096 + tid * 8);
        gld16(Wp + istep,     BS + 4096 + tid * 8 + 2048);
    }
    asm volatile("s_waitcnt vmcnt(6)" ::: "memory");   // tile 0 resident
    __builtin_amdgcn_sched_barrier(0);
    __builtin_amdgcn_s_barrier();
    __builtin_amdgcn_sched_barrier(0);

    floatx4 acc[8][4] = {};
    const unsigned short* Aga = Agp + 64;   // stages tile t+2
    const unsigned short* Wga = Wgp + 64;
    int cbA = 0, cbB = 0;                   // compute buf offsets (t%3)
    int pbA = 16384, pbB = 8192;            // prefetch buf offsets ((t+2)%3)

    for (int t = 0; t < NT; t++) {
        const bool pf = (t + 2 < NT);

        bf16x8 af[8], bf[4];
        #pragma unroll
        for (int mi = 0; mi < 8; mi++)
            af[mi] = *(const bf16x8*)(AS + cbA + c0A + mi * 512);
        #pragma unroll
        for (int ni = 0; ni < 4; ni++)
            bf[ni] = *(const bf16x8*)(BS + cbB + c0B + ni * 512);

        if (pf) {   // stage tile t+2: A x4, B x2 (FIFO order matters)
            gld16(Aga,             AS + pbA + tid * 8);
            gld16(Aga + istep,     AS + pbA + tid * 8 + 2048);
            gld16(Aga + 2 * istep, AS + pbA + tid * 8 + 4096);
            gld16(Aga + 3 * istep, AS + pbA + tid * 8 + 6144);
            gld16(Wga,             BS + pbB + tid * 8);
            gld16(Wga + istep,     BS + pbB + tid * 8 + 2048);
        }

        __builtin_amdgcn_s_setprio(1);
        #pragma unroll
        for (int mi = 0; mi < 8; mi++)
            #pragma unroll
            for (int ni = 0; ni < 4; ni++)
                acc[mi][ni] = __builtin_amdgcn_mfma_f32_16x16x32_bf16(
                    af[mi], bf[ni], acc[mi][ni], 0, 0, 0);
        __builtin_amdgcn_s_setprio(0);

        if (t + 1 < NT) {
            if (pf) asm volatile("s_waitcnt vmcnt(6)" ::: "memory");
            else    asm volatile("s_waitcnt vmcnt(0)" ::: "memory");
            __builtin_amdgcn_sched_barrier(0);
            __builtin_amdgcn_s_barrier();
            __builtin_amdgcn_sched_barrier(0);
        }
        cbA = (cbA == 16384) ? 0 : cbA + 8192;
        cbB = (cbB == 8192)  ? 0 : cbB + 4096;
        pbA = (pbA == 16384) ? 0 : pbA + 8192;
        pbB = (pbB == 8192)  ? 0 : pbB + 4096;
        Aga += 32;
        Wga += 32;
    }

    // ---- epilogue ----
    const int r0  = bm + wr * 128 + fq * 4;
    const int c0e = bn + wc * 64 + fm;
    #pragma unroll
    for (int mi = 0; mi < 8; mi++) {
        #pragma unroll
        for (int ni = 0; ni < 4; ni++) {
            const int col = c0e + ni * 16;
            const float bv = bias[col];
            #pragma unroll
            for (int rr = 0; rr < 4; rr++) {
                const int row = r0 + mi * 16 + rr;
                Co_store: ;
                float v = acc[mi][ni][rr] + bv;
                Cb[(size_t)row * 3072 + col] = f2bf(v);
            }
        }
    }
}

// ---------------------------------------------------------------------------
// gemm8p (WO/FF1/FF2): 256x256 tile, BK=64, 512 thr (8 waves 2Mx4N),
// 128KB LDS dbuf, 8-phase schedule, counted vmcnt(4) at phases 4/8.
// Verbatim from R13/R15 (passed).
// ---------------------------------------------------------------------------
__global__ __launch_bounds__(512, 2)
void gemm8p(const unsigned short* __restrict__ A,
            const unsigned short* __restrict__ Wt,
            const float* __restrict__ bias,
            unsigned short* __restrict__ Cb,
            int kstride, int kloop, int T, int tncnt,
            int ldc, int relu, size_t sstep1, size_t sstep2)
{
    __shared__ __attribute__((aligned(16))) unsigned short AS[2 * 16384];
    __shared__ __attribute__((aligned(16))) unsigned short BS[2 * 16384];

    const int id = blockIdx.x;
    const int sl = id / T;               // split-K slice
    const int t0 = id - sl * T;
    const int sid = (t0 & 7) * (T >> 3) + (t0 >> 3);   // XCD-contiguous
    const int bm = (sid / tncnt) * 256;
    const int bn = (sid % tncnt) * 256;

    const int tid  = threadIdx.x;
    const int lane = tid & 63;
    const int wave = tid >> 6;
    const int wr   = wave >> 2;          // 0..1  (M half)
    const int wc   = wave & 3;           // 0..3  (N quarter)
    const int fm   = lane & 15;
    const int fq   = lane >> 4;

    const int kofs  = sl * kloop;
    const int NITER = kloop >> 7;        // 2 K-tiles (BK=64) per iteration

    const int srow = tid >> 3;                          // 0..63
    const int scol = ((tid & 7) ^ ((tid >> 3) & 7)) * 8;
    const unsigned short* PA = A  + (size_t)(bm + srow) * kstride + kofs + scol;
    const unsigned short* PW = Wt + (size_t)(bn + srow) * kstride + kofs + scol;
    const size_t rs64 = (size_t)64 * kstride;           // +64 rows

    const int aoff = (wr * 128 + fm) * 64;
    const int boff = (wc * 64  + fm) * 64;
    const int ck0  = (fq ^ (fm & 7)) * 8;               // ks=0 chunk
    const int ck1  = ck0 ^ 32;                          // ks=1 chunk (c^4)

    floatx4 acc[8][4] = {};

    auto STG = [&](const unsigned short* g, int h, unsigned short* l) {
        gld16(g + (size_t)(2 * h)     * rs64, l + h * 8192 + tid * 8);
        gld16(g + (size_t)(2 * h + 1) * rs64, l + h * 8192 + 4096 + tid * 8);
    };
    auto rdA = [&](bf16x8 (&d)[4][2], int bufb, int mb) {
        #pragma unroll
        for (int mi = 0; mi < 4; mi++) {
            d[mi][0] = *(const bf16x8*)(AS + bufb + aoff + (mb + mi) * 1024 + ck0);
            d[mi][1] = *(const bf16x8*)(AS + bufb + aoff + (mb + mi) * 1024 + ck1);
        }
    };
    auto rdB = [&](bf16x8 (&d)[2][2], int bufb, int nb) {
        #pragma unroll
        for (int ni = 0; ni < 2; ni++) {
            d[ni][0] = *(const bf16x8*)(BS + bufb + boff + (nb + ni) * 1024 + ck0);
            d[ni][1] = *(const bf16x8*)(BS + bufb + boff + (nb + ni) * 1024 + ck1);
        }
    };
    auto mmq = [&](bf16x8 (&a)[4][2], bf16x8 (&b)[2][2], int mb, int nb) {
        __builtin_amdgcn_s_setprio(1);
        #pragma unroll
        for (int ks = 0; ks < 2; ks++)
            #pragma unroll
            for (int mi = 0; mi < 4; mi++)
                #pragma unroll
                for (int ni = 0; ni < 2; ni++)
                    acc[mb + mi][nb + ni] = __builtin_amdgcn_mfma_f32_16x16x32_bf16(
                        a[mi][ks], b[ni][ks], acc[mb + mi][nb + ni], 0, 0, 0);
        __builtin_amdgcn_s_setprio(0);
    };
    auto barpre = [&]() {
        __builtin_amdgcn_sched_barrier(0);
        __builtin_amdgcn_s_barrier();
        asm volatile("s_waitcnt lgkmcnt(0)" ::: "memory");
        __builtin_amdgcn_sched_barrier(0);
    };
    auto barpost = [&]() {
        __builtin_amdgcn_sched_barrier(0);
        __builtin_amdgcn_s_barrier();
        __builtin_amdgcn_sched_barrier(0);
    };

    unsigned short* AS0 = AS;            unsigned short* AS1 = AS + 16384;
    unsigned short* BS0 = BS;            unsigned short* BS1 = BS + 16384;

    // ---- prologue ----
    STG(PA, 0, AS0); STG(PA, 1, AS0);
    STG(PW, 0, BS0); STG(PW, 1, BS0);
    STG(PW + 64, 0, BS1); STG(PW + 64, 1, BS1);
    __builtin_amdgcn_sched_barrier(0);
    asm volatile("s_waitcnt vmcnt(4)" ::: "memory");
    __builtin_amdgcn_sched_barrier(0);
    __builtin_amdgcn_s_barrier();
    __builtin_amdgcn_sched_barrier(0);

    for (int it = 0; it < NITER; it++) {
        const bool more = (it + 1 < NITER);
        bf16x8 a03[4][2], a47[4][2], b01[2][2], b23[2][2];

        // -- p1 --
        rdA(a03, 0, 0); rdB(b01, 0, 0);
        STG(PA + 64, 0, AS1);                 // A[s+1] h0
        barpre(); mmq(a03, b01, 0, 0); barpost();
        // -- p2 --
        rdB(b23, 0, 2);
        STG(PA + 64, 1, AS1);                 // A[s+1] h1
        barpre(); mmq(a03, b23, 0, 2); barpost();
        // -- p3 --
        rdA(a47, 0, 4);
        if (more) STG(PW + 128, 0, BS0);      // B[s+2] h0
        barpre(); mmq(a47, b01, 4, 0); barpost();
        // -- p4 + certify --
        if (more) STG(PW + 128, 1, BS0);      // B[s+2] h1
        __builtin_amdgcn_sched_barrier(0);
        if (more) asm volatile("s_waitcnt vmcnt(4)" ::: "memory");
        else      asm volatile("s_waitcnt vmcnt(0)" ::: "memory");
        __builtin_amdgcn_sched_barrier(0);
        __builtin_amdgcn_s_barrier();
        __builtin_amdgcn_sched_barrier(0);
        mmq(a47, b23, 4, 2); barpost();
        // -- p5 --
        rdA(a03, 16384, 0); rdB(b01, 16384, 0);
        if (more) STG(PA + 128, 0, AS0);      // A[s+2] h0
        barpre(); mmq(a03, b01, 0, 0); barpost();
        // -- p6 --
        rdB(b23, 16384, 2);
        if (more) STG(PA + 128, 1, AS0);      // A[s+2] h1
        barpre(); mmq(a03, b23, 0, 2); barpost();
        // -- p7 --
        rdA(a47, 16384, 4);
        if (more) STG(PW + 192, 0, BS1);      // B[s+3] h0
        barpre(); mmq(a47, b01, 4, 0); barpost();
        // -- p8 + certify --
        if (more) {
            STG(PW + 192, 1, BS1);            // B[s+3] h1
            __builtin_amdgcn_sched_barrier(0);
            asm volatile("s_waitcnt vmcnt(4)" ::: "memory");
        }
        __builtin_amdgcn_sched_barrier(0);
        __builtin_amdgcn_s_barrier();
        __builtin_amdgcn_sched_barrier(0);
        mmq(a47, b23, 4, 2); barpost();

        PA += 128; PW += 128;
    }

    // ---- epilogue ----
    unsigned short* Co = Cb + (size_t)(sl & 1) * sstep1 + (size_t)(sl >> 1) * sstep2;
    const int r0  = bm + wr * 128 + fq * 4;
    const int c0e = bn + wc * 64 + fm;
    #pragma unroll
    for (int mi = 0; mi < 8; mi++) {
        #pragma unroll
        for (int ni = 0; ni < 4; ni++) {
            const int col = c0e + ni * 16;
            const float bv = bias ? bias[col] : 0.0f;
            #pragma unroll
            for (int rr = 0; rr < 4; rr++) {
                const int row = r0 + mi * 16 + rr;
                float v = acc[mi][ni][rr] + bv;
                if (relu) v = fmaxf(v, 0.0f);
                Co[(size_t)row * ldc + col] = f2bf(v);
            }
        }
    }
}

// ---------------------------------------------------------------------------
// Banded MFMA windowed attention (unchanged).
// ---------------------------------------------------------------------------
__global__ __launch_bounds__(256, 2)
void attn_mfma(const unsigned short* __restrict__ qkv,
               const float* __restrict__ rel,
               unsigned short* __restrict__ attnb)
{
    __shared__ __attribute__((aligned(16))) unsigned short Qs[64 * 72];
    __shared__ __attribute__((aligned(16))) unsigned short Ks[128 * 72];
    __shared__ __attribute__((aligned(16))) unsigned short Vt[64 * 168];
    __shared__ __attribute__((aligned(16))) unsigned short Rs[16 * 72];
    __shared__ __attribute__((aligned(16))) unsigned short Pl[4 * 16 * 104];
    __shared__ float Qrl[4 * 16 * 12];

    const int t   = threadIdx.x;
    const int blk = blockIdx.x;
    const int st  = blk & 31;
    const int h   = (blk >> 5) & 15;
    const int b   = blk >> 9;
    const int s0  = st << 6;
    const int brow0 = b * SEQ;

    const int trow = t >> 3;
    const int tc   = (t & 7) * 8;
    const uint4 z4 = make_uint4(0, 0, 0, 0);

    #pragma unroll
    for (int p = 0; p < 2; p++) {
        int r = trow + p * 32;
        uint4 v = *(const uint4*)(qkv + (size_t)(brow0 + s0 + r) * 3072 + h * 64 + tc);
        *(uint4*)(Qs + r * 72 + tc) = v;
    }
    #pragma unroll
    for (int p = 0; p < 4; p++) {
        int kr = trow + p * 32;
        int ka = s0 - 25 + kr;
        bool in = (ka >= 0) & (ka < SEQ);
        uint4 kv = z4, vv = z4;
        if (in) {
            kv = *(const uint4*)(qkv + (size_t)(brow0 + ka) * 3072 + 1024 + h * 64 + tc);
            vv = *(const uint4*)(qkv + (size_t)(brow0 + ka) * 3072 + 2048 + h * 64 + tc);
        }
        *(uint4*)(Ks + kr * 72 + tc) = kv;
        const unsigned short* e = (const unsigned short*)&vv;
        #pragma unroll
        for (int j = 0; j < 8; j++)
            Vt[(tc + j) * 168 + kr] = e[j];
    }
    if (t < 176) {
        float4 f = ((const float4*)rel)[t];
        int fi = t * 4, rr = fi >> 6, cc = fi & 63;
        ushort4 u;
        u.x = f2bf(f.x); u.y = f2bf(f.y); u.z = f2bf(f.z); u.w = f2bf(f.w);
        *(ushort4*)(Rs + rr * 72 + cc) = u;
    } else {
        int fi = 704 + (t - 176) * 4, rr = fi >> 6, cc = fi & 63;
        *(ushort4*)(Rs + rr * 72 + cc) = make_ushort4(0, 0, 0, 0);
    }
    {
        int n = t * 4, w2 = n >> 8, rem = n & 255, rr = rem >> 4, cc = 80 + (rem & 15);
        *(ushort4*)(Pl + w2 * (16 * 104) + rr * 104 + cc) = make_ushort4(0, 0, 0, 0);
    }
    for (int idx = t; idx < 320; idx += 256) {
        int r = idx / 5, cchunk = idx % 5;
        *(uint4*)(Vt + r * 168 + 128 + cchunk * 8) = z4;
    }
    __syncthreads();

    const int wave = t >> 6;
    const int lane = t & 63;
    const int fm   = lane & 15;
    const int fk8  = (lane >> 4) * 8;
    const int S0w  = s0 + wave * 16;
    unsigned short* Plw = Pl + wave * (16 * 104);
    float* Ql = Qrl + wave * (16 * 12);

    bf16x8 qa0 = *(const bf16x8*)(Qs + (wave * 16 + fm) * 72 + fk8);
    bf16x8 qa1 = *(const bf16x8*)(Qs + (wave * 16 + fm) * 72 + fk8 + 32);

    floatx4 Sc[5];
    #pragma unroll
    for (int nt = 0; nt < 5; nt++) {
        bf16x8 kb0 = *(const bf16x8*)(Ks + (wave * 16 + nt * 16 + fm) * 72 + fk8);
        bf16x8 kb1 = *(const bf16x8*)(Ks + (wave * 16 + nt * 16 + fm) * 72 + fk8 + 32);
        floatx4 acc = {0.f, 0.f, 0.f, 0.f};
        acc = __builtin_amdgcn_mfma_f32_16x16x32_bf16(qa0, kb0, acc, 0, 0, 0);
        acc = __builtin_amdgcn_mfma_f32_16x16x32_bf16(qa1, kb1, acc, 0, 0, 0);
        Sc[nt] = acc;
    }
    {
        bf16x8 rb0 = *(const bf16x8*)(Rs + fm * 72 + fk8);
        bf16x8 rb1 = *(const bf16x8*)(Rs + fm * 72 + fk8 + 32);
        floatx4 qr = {0.f, 0.f, 0.f, 0.f};
        qr = __builtin_amdgcn_mfma_f32_16x16x32_bf16(qa0, rb0, qr, 0, 0, 0);
        qr = __builtin_amdgcn_mfma_f32_16x16x32_bf16(qa1, rb1, qr, 0, 0, 0);
        if (fm < 12) {
            #pragma unroll
            for (int reg = 0; reg < 4; reg++)
                Ql[((lane >> 4) * 4 + reg) * 12 + fm] = qr[reg];
        }
    }

    float inv[4];
    const int iq0 = (lane >> 4) * 4;
    #pragma unroll
    for (int reg = 0; reg < 4; reg++) {
        const int i = iq0 + reg;
        float sc[5];
        float mx = -1e30f;
        #pragma unroll
        for (int nt = 0; nt < 5; nt++) {
            int c   = nt * 16 + fm;
            int off = c - 25 - i;
            int ka  = S0w - 25 + c;
            bool valid = (off >= -RAD) & (off <= RAD) & (ka >= 0) & (ka < SEQ);
            int rid = min(max(off, -5), 5) + 5;
            float v = valid ? (Sc[nt][reg] + Ql[i * 12 + rid]) * 0.125f : -1e30f;
            sc[nt] = v;
            mx = fmaxf(mx, v);
        }
        #pragma unroll
        for (int o = 1; o < 16; o <<= 1) mx = fmaxf(mx, __shfl_xor(mx, o));
        float sum = 0.f;
        #pragma unroll
        for (int nt = 0; nt < 5; nt++) {
            float e = __expf(sc[nt] - mx);
            sum += e;
            Plw[i * 104 + nt * 16 + fm] = f2bf(e);
        }
        #pragma unroll
        for (int o = 1; o < 16; o <<= 1) sum += __shfl_xor(sum, o);
        inv[reg] = 1.0f / sum;
    }

    floatx4 O[4] = {};
    #pragma unroll
    for (int kc = 0; kc < 3; kc++) {
        bf16x8 pa = *(const bf16x8*)(Plw + fm * 104 + fk8 + kc * 32);
        #pragma unroll
        for (int nt = 0; nt < 4; nt++) {
            bf16x8 vb = *(const bf16x8*)(Vt + (nt * 16 + fm) * 168 + wave * 16 + fk8 + kc * 32);
            O[nt] = __builtin_amdgcn_mfma_f32_16x16x32_bf16(pa, vb, O[nt], 0, 0, 0);
        }
    }

    #pragma unroll
    for (int nt = 0; nt < 4; nt++) {
        const int d = nt * 16 + fm;
        #pragma unroll
        for (int reg = 0; reg < 4; reg++) {
            const int i = iq0 + reg;
            attnb[(size_t)(brow0 + S0w + i) * 1024 + h * 64 + d] = f2bf(O[nt][reg] * inv[reg]);
        }
    }
}

// ---------------------------------------------------------------------------
// Fused (residual + 2 or 4 bf16 K-slice partials + column bias) + LayerNorm.
// ---------------------------------------------------------------------------
__global__ __launch_bounds__(256)
void ln_fuse(const float* __restrict__ resf,
             const unsigned short* __restrict__ resb,
             const unsigned short* __restrict__ p0,
             const unsigned short* __restrict__ p1,
             const unsigned short* __restrict__ p2,
             const unsigned short* __restrict__ p3,
             const float* __restrict__ cbias,
             const float* __restrict__ gamma,
             const float* __restrict__ beta,
             float* __restrict__ outf,
             unsigned short* __restrict__ outb)
{
    const int wave = threadIdx.x >> 6;
    const int lane = threadIdx.x & 63;
    const int row = blockIdx.x * 4 + wave;
    const size_t base = (size_t)row * D_MODEL;

    float x[16];
    float sum = 0.0f, sq = 0.0f;
    #pragma unroll
    for (int i = 0; i < 4; i++) {
        const int c4 = lane + i * 64;
        ushort4 u0 = ((const ushort4*)(p0 + base))[c4];
        ushort4 u1 = ((const ushort4*)(p1 + base))[c4];
        float4 cb = ((const float4*)cbias)[c4];
        float4 va;
        if (resf) {
            va = ((const float4*)(resf + base))[c4];
        } else {
            ushort4 ua = ((const ushort4*)(resb + base))[c4];
            va.x = bf2f(ua.x); va.y = bf2f(ua.y); va.z = bf2f(ua.z); va.w = bf2f(ua.w);
        }
        float e0 = va.x + bf2f(u0.x) + bf2f(u1.x) + cb.x;
        float e1 = va.y + bf2f(u0.y) + bf2f(u1.y) + cb.y;
        float e2 = va.z + bf2f(u0.z) + bf2f(u1.z) + cb.z;
        float e3 = va.w + bf2f(u0.w) + bf2f(u1.w) + cb.w;
        if (p2) {
            ushort4 u2 = ((const ushort4*)(p2 + base))[c4];
            ushort4 u3 = ((const ushort4*)(p3 + base))[c4];
            e0 += bf2f(u2.x) + bf2f(u3.x);
            e1 += bf2f(u2.y) + bf2f(u3.y);
            e2 += bf2f(u2.z) + bf2f(u3.z);
            e3 += bf2f(u2.w) + bf2f(u3.w);
        }
        x[i*4+0] = e0; x[i*4+1] = e1; x[i*4+2] = e2; x[i*4+3] = e3;
        sum += e0 + e1 + e2 + e3;
        sq  += e0*e0 + e1*e1 + e2*e2 + e3*e3;
    }
    #pragma unroll
    for (int off = 32; off > 0; off >>= 1) {
        sum += __shfl_xor(sum, off);
        sq  += __shfl_xor(sq,  off);
    }
    const float mean = sum * (1.0f / 1024.0f);
    const float var  = sq  * (1.0f / 1024.0f) - mean * mean;
    const float rs   = rsqrtf(var + 1e-5f);

    #pragma unroll
    for (int i = 0; i < 4; i++) {
        const int c4 = lane + i * 64;
        float4 g4 = ((const float4*)gamma)[c4];
        float4 b4 = ((const float4*)beta)[c4];
        float4 o;
        o.x = (x[i*4+0] - mean) * rs * g4.x + b4.x;
        o.y = (x[i*4+1] - mean) * rs * g4.y + b4.y;
        o.z = (x[i*4+2] - mean) * rs * g4.z + b4.z;
        o.w = (x[i*4+3] - mean) * rs * g4.w + b4.w;
        if (outf) ((float4*)(outf + base))[c4] = o;
        if (outb) {
            ushort4 u;
            u.x = f2bf(o.x); u.y = f2bf(o.y); u.z = f2bf(o.z); u.w = f2bf(o.w);
            ((ushort4*)(outb + base))[c4] = u;
        }
    }
}

// ---------------------------------------------------------------------------
extern "C" void kernel_launch(void* const* d_in, const int* in_sizes, int n_in,
                              void* d_out, int out_size, void* d_ws, size_t ws_size,
                              hipStream_t stream)
{
    const float* src = (const float*)d_in[0];
    const float* wq  = (const float*)d_in[1];
    const float* bq  = (const float*)d_in[2];
    const float* wk  = (const float*)d_in[3];
    const float* bk  = (const float*)d_in[4];
    const float* wv  = (const float*)d_in[5];
    const float* bv  = (const float*)d_in[6];
    const float* wo  = (const float*)d_in[7];
    const float* bo  = (const float*)d_in[8];
    const float* rel = (const float*)d_in[9];
    const float* w1  = (const float*)d_in[10];
    const float* b1  = (const float*)d_in[11];
    const float* w2  = (const float*)d_in[12];
    const float* b2  = (const float*)d_in[13];
    const float* g1  = (const float*)d_in[14];
    const float* be1 = (const float*)d_in[15];
    const float* g2  = (const float*)d_in[16];
    const float* be2 = (const float*)d_in[17];
    float* out = (float*)d_out;

    char* ws = (char*)d_ws;
    const size_t MB = 1048576;
    // Layout (peak 89 MB) — identical to R13/R15:
    //  0..6   wqkvb (dead after QKV) | reused by FF2 partials 0,1
    //  6..8   wob   (dead after WO)
    //  8..16  w1b   (dead after FF1)
    // 16..24  w2b   (live through FF2)
    // 24..25  bqkv  (dead after QKV) | reused by FF2 partials 2,3
    // 25..33  xb / attnb (dead after WO)
    // 33..57  qkvb  (dead after attn)
    // 33..49  WO partials 0,1 (dead after ln1)
    // 57..73  WO partials 2,3 (dead after ln1; inside ff1b, written later)
    // 49..57  x1b   (live through ln2)
    // 57..89  ff1b  (live through FF2)
    unsigned short* wqkvb = (unsigned short*)(ws + 0);
    unsigned short* wob   = (unsigned short*)(ws + 6  * MB);
    unsigned short* w1b   = (unsigned short*)(ws + 8  * MB);
    unsigned short* w2b   = (unsigned short*)(ws + 16 * MB);
    float*          bqkv  = (float*)         (ws + 24 * MB);
    unsigned short* xb    = (unsigned short*)(ws + 25 * MB);
    unsigned short* attnb = xb;
    unsigned short* qkvb  = (unsigned short*)(ws + 33 * MB);
    unsigned short* z01   = (unsigned short*)(ws + 33 * MB);
    unsigned short* x1b   = (unsigned short*)(ws + 49 * MB);
    unsigned short* ff1b  = (unsigned short*)(ws + 57 * MB);
    unsigned short* f01   = (unsigned short*)(ws + 0);        // FF2 slices 0,1
    const size_t SL    = (size_t)NROWS * 1024;   // 8 MB slice (ushort elems)
    const size_t SOFF2 = (size_t)12 * MB;        // ushort elems == 24 MB bytes

    const dim3 blk(256);
    const dim3 blk5(512);
    // cvt1: src + wq/wk/wv + biases only (what QKV needs)
    cvt1<<<7169, blk, 0, stream>>>(src, wq, wk, wv, bq, bk, bv, xb, wqkvb, bqkv);
    // QKV GEMM (blocks 0..383) + wo/w1/w2 conversion (blocks 384..9599)
    qkv_cvt<<<9600, blk, 0, stream>>>(xb, wqkvb, bqkv, qkvb,
                                      wo, w1, w2, wob, w1b, w2b);
    attn_mfma<<<1024, blk, 0, stream>>>(qkvb, rel, attnb);
    // WO: 4096x1024, K=1024 split 4 (gemm8p, grid 256) -> partials {33,41,57,65} MB
    gemm8p<<<256, blk5, 0, stream>>>(attnb, wob, nullptr, z01, 1024, 256, 64, 4,
                                     1024, 0, SL, SOFF2);
    // x1 = LN(src + z0 + z1 + z2 + z3 + bo)
    ln_fuse<<<NROWS / 4, blk, 0, stream>>>(src, nullptr, z01, z01 + SL,
                                           z01 + SOFF2, z01 + SOFF2 + SL,
                                           bo, g1, be1, nullptr, x1b);
    // FF1: 4096x4096, K=1024, relu+bias (gemm8p, grid 256, 16x16 tiles of 256^2)
    gemm8p<<<256, blk5, 0, stream>>>(x1b, w1b, b1, ff1b, 1024, 1024, 256, 16,
                                     4096, 1, 0, 0);
    // FF2: 4096x1024, K=4096 split 4 (gemm8p, grid 256) -> partials {0,8,24,32} MB
    gemm8p<<<256, blk5, 0, stream>>>(ff1b, w2b, nullptr, f01, 4096, 1024, 64, 4,
                                     1024, 0, SL, SOFF2);
    // out = LN(x1 + f0 + f1 + f2 + f3 + b2)
    ln_fuse<<<NROWS / 4, blk, 0, stream>>>(nullptr, x1b, f01, f01 + SL,
                                           f01 + SOFF2, f01 + SOFF2 + SL,
                                           b2, g2, be2, out, nullptr);
}